// Round 3
// baseline (792.611 us; speedup 1.0000x reference)
//
#include <hip/hip_runtime.h>
#include <hip/hip_bf16.h>
#include <cstdio>

// Problem dims
#define BS   2
#define LL   2048
#define HH   8
#define PP   64
#define NQ   300          // d_state / num queries
#define NPAD 304
#define SLICE 19          // per-wave n-slice (8 waves * 19 = 152 per block, 2 blocks cover 304)
#define TT   128          // chunk length
#define NCH  16           // L / TT
#define DI   512
#define DKEY 1034

// ---------------------------------------------------------------------------
// Generic GEMM-NT: C[m,n] = sum_k A[m*lda+k] * B[n*ldb+k]  (64x64 tile)
// ---------------------------------------------------------------------------
__global__ __launch_bounds__(256) void gemm_nt(
    const float* __restrict__ A, const float* __restrict__ Bm, float* __restrict__ C,
    int M, int N, int K, int lda, int ldb, int ldc)
{
    __shared__ float As[16][68];
    __shared__ float Bs[16][68];
    const int tid = threadIdx.x;
    const int tx = tid & 15, ty = tid >> 4;
    const int m0 = blockIdx.x * 64, n0 = blockIdx.y * 64;
    const int lr = tid >> 2, lk = (tid & 3) << 2;
    float acc[4][4] = {};
    for (int k0 = 0; k0 < K; k0 += 16) {
        float4 av = make_float4(0.f,0.f,0.f,0.f), bv = make_float4(0.f,0.f,0.f,0.f);
        int am = m0 + lr;
        if (am < M) av = *(const float4*)(A + (size_t)am * lda + k0 + lk);
        int bn = n0 + lr;
        if (bn < N) bv = *(const float4*)(Bm + (size_t)bn * ldb + k0 + lk);
        __syncthreads();
        As[lk+0][lr] = av.x; As[lk+1][lr] = av.y; As[lk+2][lr] = av.z; As[lk+3][lr] = av.w;
        Bs[lk+0][lr] = bv.x; Bs[lk+1][lr] = bv.y; Bs[lk+2][lr] = bv.z; Bs[lk+3][lr] = bv.w;
        __syncthreads();
        #pragma unroll
        for (int kk = 0; kk < 16; ++kk) {
            float a0 = As[kk][ty*4+0], a1 = As[kk][ty*4+1], a2 = As[kk][ty*4+2], a3 = As[kk][ty*4+3];
            float b0 = Bs[kk][tx*4+0], b1 = Bs[kk][tx*4+1], b2 = Bs[kk][tx*4+2], b3 = Bs[kk][tx*4+3];
            acc[0][0] = fmaf(a0,b0,acc[0][0]); acc[0][1] = fmaf(a0,b1,acc[0][1]);
            acc[0][2] = fmaf(a0,b2,acc[0][2]); acc[0][3] = fmaf(a0,b3,acc[0][3]);
            acc[1][0] = fmaf(a1,b0,acc[1][0]); acc[1][1] = fmaf(a1,b1,acc[1][1]);
            acc[1][2] = fmaf(a1,b2,acc[1][2]); acc[1][3] = fmaf(a1,b3,acc[1][3]);
            acc[2][0] = fmaf(a2,b0,acc[2][0]); acc[2][1] = fmaf(a2,b1,acc[2][1]);
            acc[2][2] = fmaf(a2,b2,acc[2][2]); acc[2][3] = fmaf(a2,b3,acc[2][3]);
            acc[3][0] = fmaf(a3,b0,acc[3][0]); acc[3][1] = fmaf(a3,b1,acc[3][1]);
            acc[3][2] = fmaf(a3,b2,acc[3][2]); acc[3][3] = fmaf(a3,b3,acc[3][3]);
        }
    }
    #pragma unroll
    for (int i = 0; i < 4; ++i) {
        int m = m0 + ty*4 + i;
        if (m >= M) continue;
        #pragma unroll
        for (int j = 0; j < 4; ++j) {
            int n = n0 + tx*4 + j;
            if (n < N) C[(size_t)m * ldc + n] = acc[i][j];
        }
    }
}

// ---------------------------------------------------------------------------
// Bigger GEMM-NT: 128x64 tile, 256 threads, 8x4 micro-tile (VALU-dominant).
// ---------------------------------------------------------------------------
__global__ __launch_bounds__(256) void gemm_nt_big(
    const float* __restrict__ A, const float* __restrict__ Bm, float* __restrict__ C,
    int M, int N, int K, int lda, int ldb, int ldc)
{
    __shared__ float As[16][132];
    __shared__ float Bs[16][68];
    const int tid = threadIdx.x;
    const int tx = tid & 15, ty = tid >> 4;
    const int m0 = blockIdx.x * 128, n0 = blockIdx.y * 64;
    const int lr = tid >> 2, lk = (tid & 3) << 2;
    float acc[8][4] = {};
    for (int k0 = 0; k0 < K; k0 += 16) {
        float4 a0v = make_float4(0.f,0.f,0.f,0.f), a1v = a0v, bv = a0v;
        int am0 = m0 + lr, am1 = m0 + 64 + lr;
        if (am0 < M) a0v = *(const float4*)(A + (size_t)am0 * lda + k0 + lk);
        if (am1 < M) a1v = *(const float4*)(A + (size_t)am1 * lda + k0 + lk);
        int bn = n0 + lr;
        if (bn < N) bv = *(const float4*)(Bm + (size_t)bn * ldb + k0 + lk);
        __syncthreads();
        As[lk+0][lr] = a0v.x; As[lk+1][lr] = a0v.y; As[lk+2][lr] = a0v.z; As[lk+3][lr] = a0v.w;
        As[lk+0][64+lr] = a1v.x; As[lk+1][64+lr] = a1v.y; As[lk+2][64+lr] = a1v.z; As[lk+3][64+lr] = a1v.w;
        Bs[lk+0][lr] = bv.x; Bs[lk+1][lr] = bv.y; Bs[lk+2][lr] = bv.z; Bs[lk+3][lr] = bv.w;
        __syncthreads();
        #pragma unroll
        for (int kk = 0; kk < 16; ++kk) {
            float a[8], b[4];
            #pragma unroll
            for (int i = 0; i < 8; ++i) a[i] = As[kk][ty*8+i];
            #pragma unroll
            for (int j = 0; j < 4; ++j) b[j] = Bs[kk][tx*4+j];
            #pragma unroll
            for (int i = 0; i < 8; ++i)
                #pragma unroll
                for (int j = 0; j < 4; ++j)
                    acc[i][j] = fmaf(a[i], b[j], acc[i][j]);
        }
    }
    #pragma unroll
    for (int i = 0; i < 8; ++i) {
        int m = m0 + ty*8 + i;
        if (m >= M) continue;
        #pragma unroll
        for (int j = 0; j < 4; ++j) {
            int n = n0 + tx*4 + j;
            if (n < N) C[(size_t)m * ldc + n] = acc[i][j];
        }
    }
}

// ---------------------------------------------------------------------------
// dt / B / C precompute. Writes packed coefficient pairs {a=exp(dt*A), u=dt*B}
// per (b,h,l,n) and C per (b,l,n), both padded to NPAD (pads: a=1,u=0,c=0).
// ---------------------------------------------------------------------------
__global__ __launch_bounds__(256) void dtbc_kernel(
    const float* __restrict__ dist, const float* __restrict__ zx,
    const float* __restrict__ W_bc, const float* __restrict__ W_dt,
    const float* __restrict__ dt_bias, const float* __restrict__ A_log,
    float2* __restrict__ pairs, float* __restrict__ Cc)
{
    const int r = blockIdx.x;           // b*LL + l
    const int b = r >> 11, l = r & 2047;
    const int tid = threadIdx.x;
    const float bb = zx[(size_t)r*DKEY + 1024];
    const float cb = zx[(size_t)r*DKEY + 1025];
    #pragma unroll
    for (int rep = 0; rep < 2; ++rep) {
        int n = rep*256 + tid;
        if (n >= NPAD) break;
        if (n < NQ) {
            const float4* dp = (const float4*)(dist + ((size_t)r*NQ + n)*16);
            float d[16];
            #pragma unroll
            for (int j = 0; j < 4; ++j) {
                float4 v = dp[j];
                d[4*j+0]=v.x; d[4*j+1]=v.y; d[4*j+2]=v.z; d[4*j+3]=v.w;
            }
            float Bv = bb, Cv = cb;
            #pragma unroll
            for (int j = 0; j < 16; ++j) {
                Bv = fmaf(d[j], W_bc[j],     Bv);
                Cv = fmaf(d[j], W_bc[16+j],  Cv);
            }
            Cc[(size_t)r*NPAD + n] = Cv;
            #pragma unroll
            for (int h = 0; h < HH; ++h) {
                float s = zx[(size_t)r*DKEY + 1026 + h] + dt_bias[h];
                #pragma unroll
                for (int j = 0; j < 16; ++j) s = fmaf(d[j], W_dt[h*16+j], s);
                float dtv = (s > 20.f) ? s : log1pf(expf(s));
                float Ah = -expf(A_log[h]);
                pairs[((size_t)(b*HH+h)*LL + l)*NPAD + n] = make_float2(expf(dtv*Ah), dtv*Bv);
            }
        } else {
            Cc[(size_t)r*NPAD + n] = 0.f;
            #pragma unroll
            for (int h = 0; h < HH; ++h)
                pairs[((size_t)(b*HH+h)*LL + l)*NPAD + n] = make_float2(1.f, 0.f);
        }
    }
}

// ---------------------------------------------------------------------------
// Quarter-chunk decay products: Adec4[bh][c][q][n] = prod over 32 steps.
// 1024 blocks for latency hiding; chunkscan multiplies the 4 partials.
// ---------------------------------------------------------------------------
__global__ __launch_bounds__(320) void adec_kernel(
    const float2* __restrict__ pairs, float* __restrict__ Adec4)
{
    const int bid = blockIdx.x;        // q + 4*(c + 16*bh)
    const int q = bid & 3, c = (bid >> 2) & 15, bh = bid >> 6;
    const int n = threadIdx.x;
    if (n >= NPAD) return;
    const float2* pr = pairs + ((size_t)bh*LL + c*TT + q*32)*NPAD + n;
    float prod = 1.f;
    #pragma unroll 8
    for (int t = 0; t < 32; ++t) prod *= pr[(size_t)t*NPAD].x;
    Adec4[(((size_t)bh*NCH + c)*4 + q)*NPAD + n] = prod;
}

// ---------------------------------------------------------------------------
// Sweep A: intra-chunk scan from zero state. block = (dir,b,h,chunk,nhalf),
// 512 thr, 4 blocks/CU (100% occupancy). Wave w owns 19 n's; lane = p.
// Coefficients via s_load (wave-uniform) broadcast from SGPRs.
// ---------------------------------------------------------------------------
__global__ __launch_bounds__(512, 8) void sweepA(
    const float2* __restrict__ pairs, const float* __restrict__ Cc,
    const float* __restrict__ zx,
    float* __restrict__ Sloc,
    float* __restrict__ y00, float* __restrict__ y01,
    float* __restrict__ y10, float* __restrict__ y11)
{
    const int bid = blockIdx.x;
    const int nh = bid & 1, c = (bid >> 1) & 15, h = (bid >> 5) & 7;
    const int b = (bid >> 8) & 1, dir = bid >> 9;
    const int tid = threadIdx.x;
    const int p = tid & 63;
    const int w = __builtin_amdgcn_readfirstlane(tid >> 6);
    const int n0 = nh*152 + w * SLICE;              // wave-uniform
    float* __restrict__ ybuf = dir ? (nh ? y11 : y10) : (nh ? y01 : y00);

    __shared__ float yred[8*512];

    float S[SLICE];
    #pragma unroll
    for (int i = 0; i < SLICE; ++i) S[i] = 0.f;

    const size_t prow = (size_t)(b*HH + h) * LL;    // pairs row base (in l)
    int l0 = dir ? (LL-1 - c*TT) : c*TT;
    float xp = zx[(size_t)(b*LL + l0)*DKEY + 512 + h*PP + p];

    for (int t = 0; t < TT; ++t) {
        const int ls = c*TT + t;
        const int l  = dir ? (LL-1-ls) : ls;
        float xnext = 0.f;
        if (t + 1 < TT) {
            int l2 = dir ? (l - 1) : (l + 1);
            xnext = zx[(size_t)(b*LL + l2)*DKEY + 512 + h*PP + p];
        }
        const float2* __restrict__ pr = pairs + ((prow + l)*NPAD) + n0;      // uniform
        const float*  __restrict__ cw = Cc + ((size_t)(b*LL + l)*NPAD) + n0; // uniform
        float yp = 0.f;
        #pragma unroll
        for (int i = 0; i < SLICE; ++i) {
            float2 au = pr[i];          // s_load: broadcast via SGPR
            float  cv = cw[i];          // s_load
            S[i] = fmaf(S[i], au.x, au.y * xp);
            yp   = fmaf(S[i], cv, yp);
        }
        yred[(t & 7)*512 + tid] = yp;
        if ((t & 7) == 7) {
            __syncthreads();
            int sl = tid >> 6, pp2 = tid & 63;
            float sum = 0.f;
            #pragma unroll
            for (int wv = 0; wv < 8; ++wv) sum += yred[sl*512 + wv*64 + pp2];
            int ts  = t - 7 + sl;
            int ls2 = c*TT + ts;
            int l2  = dir ? (LL-1-ls2) : ls2;
            ybuf[((size_t)(b*LL + l2)*HH + h)*PP + pp2] = sum;
            __syncthreads();
        }
        xp = xnext;
    }
    // chunk-end state
    const size_t sbase = (((size_t)((dir*BS + b)*HH + h)*NCH + c)*NQ)*PP;
    #pragma unroll
    for (int i = 0; i < SLICE; ++i) {
        int n = n0 + i;
        if (n < NQ) Sloc[sbase + (size_t)n*PP + p] = S[i];
    }
}

// ---------------------------------------------------------------------------
// Inter-chunk scan: carry[c] = state before chunk c; carry[NCH] = final state.
// Adec4 is direction-shared: bwd chunk cc uses fwd chunk (NCH-1-cc).
// ---------------------------------------------------------------------------
__global__ __launch_bounds__(256) void chunkscan(
    const float* __restrict__ Sloc, const float* __restrict__ Adec4,
    const float* __restrict__ proj, float* __restrict__ carry)
{
    const int bid = blockIdx.x;          // 2400 = 32 * 75
    const int dbh = bid / 75;            // dir*16 + b*8 + h
    const int tile = bid % 75;
    const int e = tile*256 + threadIdx.x;   // < 19200
    const int n = e >> 6, p = e & 63;
    const int h = dbh & 7, b = (dbh >> 3) & 1, dir = dbh >> 4;
    const int bh = dbh & 15;
    float cur = proj[((size_t)(b*NQ + n))*DI + h*PP + p];   // init state
    const size_t cbase = (size_t)dbh * (NCH+1) * NQ * PP;
    const size_t sbase = (size_t)dbh * NCH * NQ * PP;
    carry[cbase + e] = cur;
    #pragma unroll
    for (int cc = 0; cc < NCH; ++cc) {
        int cF = dir ? (NCH-1-cc) : cc;
        const float* a4 = Adec4 + (((size_t)bh*NCH + cF)*4)*NPAD + n;
        float ad = a4[0] * a4[NPAD] * a4[2*NPAD] * a4[3*NPAD];
        cur = fmaf(cur, ad, Sloc[sbase + (size_t)cc*NQ*PP + e]);
        carry[cbase + (size_t)(cc+1)*NQ*PP + e] = cur;
    }
}

// ---------------------------------------------------------------------------
// Sweep B: y += sum_n C[l,n] * beta[l,n] * carry[n,p], with beta folded into
// the carry registers (cr *= a each step).
// ---------------------------------------------------------------------------
__global__ __launch_bounds__(512, 8) void sweepB(
    const float2* __restrict__ pairs, const float* __restrict__ Cc,
    const float* __restrict__ carry,
    float* __restrict__ y00, float* __restrict__ y01,
    float* __restrict__ y10, float* __restrict__ y11)
{
    const int bid = blockIdx.x;
    const int nh = bid & 1, c = (bid >> 1) & 15, h = (bid >> 5) & 7;
    const int b = (bid >> 8) & 1, dir = bid >> 9;
    const int tid = threadIdx.x;
    const int p = tid & 63;
    const int w = __builtin_amdgcn_readfirstlane(tid >> 6);
    const int n0 = nh*152 + w * SLICE;
    float* __restrict__ ybuf = dir ? (nh ? y11 : y10) : (nh ? y01 : y00);

    __shared__ float yred[8*512];

    const size_t cbase = (((size_t)((dir*BS + b)*HH + h)*(NCH+1) + c)*NQ)*PP;
    float cr[SLICE];
    #pragma unroll
    for (int i = 0; i < SLICE; ++i) {
        int n = n0 + i;
        cr[i] = (n < NQ) ? carry[cbase + (size_t)n*PP + p] : 0.f;
    }

    const size_t prow = (size_t)(b*HH + h) * LL;

    for (int t = 0; t < TT; ++t) {
        const int ls = c*TT + t;
        const int l  = dir ? (LL-1-ls) : ls;
        const float2* __restrict__ pr = pairs + ((prow + l)*NPAD) + n0;      // uniform
        const float*  __restrict__ cw = Cc + ((size_t)(b*LL + l)*NPAD) + n0; // uniform
        float yc = 0.f;
        #pragma unroll
        for (int i = 0; i < SLICE; ++i) {
            float a  = pr[i].x;         // s_load
            float cv = cw[i];           // s_load
            cr[i] *= a;                 // fold decay into carry
            yc = fmaf(cr[i], cv, yc);
        }
        yred[(t & 7)*512 + tid] = yc;
        if ((t & 7) == 7) {
            __syncthreads();
            int sl = tid >> 6, pp2 = tid & 63;
            float sum = 0.f;
            #pragma unroll
            for (int wv = 0; wv < 8; ++wv) sum += yred[sl*512 + wv*64 + pp2];
            int ts  = t - 7 + sl;
            int ls2 = c*TT + ts;
            int l2  = dir ? (LL-1-ls2) : ls2;
            size_t yi = ((size_t)(b*LL + l2)*HH + h)*PP + pp2;
            ybuf[yi] += sum;
            __syncthreads();
        }
    }
}

// ---------------------------------------------------------------------------
// Gated RMSNorm over 4 y-partials:
// g = (0.5*(y00+y01+y10+y11) + x*D) * silu(z); kf = g*rsqrt(mean g^2+eps)*w
// ---------------------------------------------------------------------------
__global__ __launch_bounds__(256) void gate_rms(
    const float* __restrict__ zx,
    const float* __restrict__ y00, const float* __restrict__ y01,
    const float* __restrict__ y10, const float* __restrict__ y11,
    const float* __restrict__ Dp,
    const float* __restrict__ knw, float* __restrict__ kfn)
{
    const int r = blockIdx.x, tid = threadIdx.x;
    __shared__ float part[4];
    float g[2];
    #pragma unroll
    for (int rep = 0; rep < 2; ++rep) {
        int dcol = rep*256 + tid;
        size_t yi = (size_t)r*DI + dcol;
        float zv = zx[(size_t)r*DKEY + dcol];
        float xv = zx[(size_t)r*DKEY + 512 + dcol];
        float yv = 0.5f*(y00[yi] + y01[yi] + y10[yi] + y11[yi]) + xv * Dp[dcol >> 6];
        float sig = 1.f / (1.f + expf(-zv));
        g[rep] = yv * (zv * sig);
    }
    float ss = g[0]*g[0] + g[1]*g[1];
    #pragma unroll
    for (int o = 32; o; o >>= 1) ss += __shfl_xor(ss, o, 64);
    if ((tid & 63) == 0) part[tid >> 6] = ss;
    __syncthreads();
    float tot = part[0] + part[1] + part[2] + part[3];
    float scale = rsqrtf(tot * (1.f/512.f) + 1e-5f);
    #pragma unroll
    for (int rep = 0; rep < 2; ++rep) {
        int dcol = rep*256 + tid;
        kfn[(size_t)r*DI + dcol] = g[rep] * scale * knw[dcol];
    }
}

// ---------------------------------------------------------------------------
// Final-state LayerNorm: lastn[b,q,(h,p)] from 0.5*(Sf+Sb)
// ---------------------------------------------------------------------------
__global__ __launch_bounds__(512) void state_ln(
    const float* __restrict__ carry, const float* __restrict__ qw,
    const float* __restrict__ qb, float* __restrict__ lastn)
{
    const int row = blockIdx.x;          // b*NQ + q
    const int b = row / NQ, q = row % NQ;
    const int tid = threadIdx.x;         // 512
    const int h = tid >> 6, p = tid & 63;
    __shared__ float pm[8], pv[8];
    size_t iF = ((((size_t)((0*BS + b)*HH + h))*(NCH+1) + NCH)*NQ + q)*PP + p;
    size_t iB = ((((size_t)((1*BS + b)*HH + h))*(NCH+1) + NCH)*NQ + q)*PP + p;
    float v = 0.5f * (carry[iF] + carry[iB]);
    float s1 = v, s2 = v*v;
    #pragma unroll
    for (int o = 32; o; o >>= 1) { s1 += __shfl_xor(s1, o, 64); s2 += __shfl_xor(s2, o, 64); }
    if ((tid & 63) == 0) { pm[tid >> 6] = s1; pv[tid >> 6] = s2; }
    __syncthreads();
    float m = 0.f, s = 0.f;
    #pragma unroll
    for (int i = 0; i < 8; ++i) { m += pm[i]; s += pv[i]; }
    m *= (1.f/512.f);
    s = s*(1.f/512.f) - m*m;
    lastn[(size_t)row*DI + tid] = (v - m)*rsqrtf(s + 1e-5f)*qw[tid] + qb[tid];
}

// ---------------------------------------------------------------------------
extern "C" void kernel_launch(void* const* d_in, const int* in_sizes, int n_in,
                              void* d_out, int out_size, void* d_ws, size_t ws_size,
                              hipStream_t stream)
{
    const float* in_key    = (const float*)d_in[0];
    const float* in_query  = (const float*)d_in[1];
    const float* dist      = (const float*)d_in[2];
    const float* W_key     = (const float*)d_in[3];
    const float* W_query   = (const float*)d_in[4];
    const float* W_bc      = (const float*)d_in[5];
    const float* W_dt      = (const float*)d_in[6];
    const float* dt_bias   = (const float*)d_in[7];
    const float* A_log     = (const float*)d_in[8];
    const float* Dp        = (const float*)d_in[9];
    const float* W_out_key = (const float*)d_in[10];
    const float* W_out_qry = (const float*)d_in[11];
    const float* knw       = (const float*)d_in[12];
    const float* qw        = (const float*)d_in[13];
    const float* qb        = (const float*)d_in[14];
    float* out = (float*)d_out;

    float* ws = (float*)d_ws;
    size_t off = 0;
    auto alloc = [&](size_t nf) { float* pp = ws + off; off += nf; return pp; };
    float*  zx    = alloc((size_t)4096*DKEY);             // 4.24M
    float*  proj  = alloc((size_t)600*DI);                // 0.31M
    float2* pairs = (float2*)alloc((size_t)16*LL*NPAD*2); // 19.9M floats
    float*  Cc    = alloc((size_t)BS*LL*NPAD);            // 1.25M
    float*  Sloc  = alloc((size_t)32*NCH*NQ*PP);          // 9.83M (reused for kfn/lastn)
    float*  Adec4 = alloc((size_t)16*NCH*4*NPAD);         // 0.31M
    float*  carry = alloc((size_t)32*(NCH+1)*NQ*PP);      // 10.4M
    float*  y00   = alloc((size_t)BS*LL*DI);              // 2.1M
    float*  y01   = alloc((size_t)BS*LL*DI);              // 2.1M
    float*  y10   = alloc((size_t)BS*LL*DI);              // 2.1M
    float*  y11   = alloc((size_t)BS*LL*DI);              // 2.1M
    // kfn / lastn alias onto Sloc (dead after chunkscan)
    float*  kfn   = Sloc;
    float*  lastn = Sloc + (size_t)4096*DI;
    if (off * sizeof(float) > ws_size) {
        fprintf(stderr, "kernel_launch: workspace too small: need %zu bytes, have %zu\n",
                off * sizeof(float), ws_size);
        return;
    }

    dim3 blk(256);
    // K1: zxbcdt = in_key @ W_key^T   [4096 x 1034]
    gemm_nt_big<<<dim3(32, 17), blk, 0, stream>>>(in_key, W_key, zx, 4096, DKEY, 256, 256, 256, DKEY);
    // K2: init = in_query @ W_query^T  [600 x 512]
    gemm_nt<<<dim3(10, 8), blk, 0, stream>>>(in_query, W_query, proj, 600, DI, 256, 256, 256, DI);
    // K3: coefficient precompute
    dtbc_kernel<<<4096, blk, 0, stream>>>(dist, zx, W_bc, W_dt, dt_bias, A_log, pairs, Cc);
    // K3b: quarter-chunk decay products (dir-shared)
    adec_kernel<<<1024, dim3(320), 0, stream>>>(pairs, Adec4);
    // K4: intra-chunk scans (both directions, n-split)
    sweepA<<<1024, dim3(512), 0, stream>>>(pairs, Cc, zx, Sloc, y00, y01, y10, y11);
    // K5: inter-chunk scan
    chunkscan<<<2400, blk, 0, stream>>>(Sloc, Adec4, proj, carry);
    // K6: carry corrections into y
    sweepB<<<1024, dim3(512), 0, stream>>>(pairs, Cc, carry, y00, y01, y10, y11);
    // K7: gated RMSNorm + out_key projection
    gate_rms<<<4096, blk, 0, stream>>>(zx, y00, y01, y10, y11, Dp, knw, kfn);
    gemm_nt<<<dim3(64, 4), blk, 0, stream>>>(kfn, W_out_key, out, 4096, 256, DI, DI, DI, 256);
    // K8: final-state LayerNorm + out_query projection
    state_ln<<<600, dim3(512), 0, stream>>>(carry, qw, qb, lastn);
    gemm_nt<<<dim3(10, 4), blk, 0, stream>>>(lastn, W_out_qry, out + (size_t)4096*256, 600, 256, DI, DI, DI, 256);
}